// Round 3
// baseline (148.242 us; speedup 1.0000x reference)
//
#include <hip/hip_runtime.h>
#include <math.h>

#define NN 8192
#define JT 256                         // j-tile width = block size
#define IC 64                          // i-chunk per block
#define NJT (NN / JT)                  // 32 j-tiles
#define NBLOCKS (2 * NJT * (NJT + 1))  // sum_t 4(t+1) = 2112 blocks
#define ALPHA_C 3.0f
#define MIN_DIFF_C 0.1f
#define LOG2E 1.44269504088896340736f
#define LN2   0.69314718055994530942f

// Block b covers j in [t*256, t*256+256) x i in [ic*64, ic*64+64), ic in
// [0, 4(t+1)). Chunks with ic >= 4t overlap the diagonal -> predicate i<j.
// i-values are wave-uniform broadcast loads (L1), no LDS in the hot loop.
// -log_sigmoid(x) = ln2 * log2(1 + 2^(-x*log2e)); ln2 applied in finalize.
// Partials -> parts[b] (float4: pair_sum', count, reg_sum). No atomics.
__global__ __launch_bounds__(256, 8) void pair_kernel(
    const float* __restrict__ pred, const float* __restrict__ targ,
    float4* __restrict__ parts) {
    const int b = blockIdx.x;
    // decode b -> (t, ic): blocks before tile t = 2*t*(t+1)
    int t = (int)((sqrt(1.0 + 2.0 * (double)b) - 1.0) * 0.5);
    while (2 * (t + 1) * (t + 2) <= b) ++t;
    while (2 * t * (t + 1) > b) --t;
    const int ic = b - 2 * t * (t + 1);
    const int j0 = t * JT;
    const int i0 = ic * IC;

    const int tid = threadIdx.x;
    const int j = j0 + tid;
    const float pj   = pred[j];
    const float tjv  = targ[j];
    const float npjl = -pj * LOG2E;  // so (pi - pj)*log2e = fma(pi, log2e, npjl)

    float s = 0.0f;  // sum of conf * log2(1+2^-y)  (missing ln2 factor)
    float c = 0.0f;  // masked pair count
    float r = 0.0f;  // regression partial

    const bool diag = (ic >= 4 * t);

    if (!diag) {
        #pragma unroll
        for (int ch = 0; ch < IC / 8; ++ch) {
            const float4 pa = *(const float4*)(pred + i0 + ch * 8);
            const float4 pb = *(const float4*)(pred + i0 + ch * 8 + 4);
            const float4 ta = *(const float4*)(targ + i0 + ch * 8);
            const float4 tb = *(const float4*)(targ + i0 + ch * 8 + 4);
            const float pi[8] = {pa.x, pa.y, pa.z, pa.w, pb.x, pb.y, pb.z, pb.w};
            const float ti[8] = {ta.x, ta.y, ta.z, ta.w, tb.x, tb.y, tb.z, tb.w};
            #pragma unroll
            for (int k = 0; k < 8; ++k) {
                const float dt  = ti[k] - tjv;
                const float dps = fmaf(pi[k], LOG2E, npjl);   // (pi-pj)*log2e
                const float ny  = (dt < 0.0f) ? dps : -dps;   // -(dps*sgn(dt))
                const float e   = __builtin_amdgcn_exp2f(ny); // 2^-y, <= ~2^15
                const float lg  = __builtin_amdgcn_logf(1.0f + e);
                const bool valid = fabsf(dt) > MIN_DIFF_C;
                s = fmaf(valid ? fabsf(dt) : 0.0f, lg, s);
                c += valid ? 1.0f : 0.0f;
            }
        }
    } else {
        #pragma unroll
        for (int ch = 0; ch < IC / 8; ++ch) {
            const float4 pa = *(const float4*)(pred + i0 + ch * 8);
            const float4 pb = *(const float4*)(pred + i0 + ch * 8 + 4);
            const float4 ta = *(const float4*)(targ + i0 + ch * 8);
            const float4 tb = *(const float4*)(targ + i0 + ch * 8 + 4);
            const float pi[8] = {pa.x, pa.y, pa.z, pa.w, pb.x, pb.y, pb.z, pb.w};
            const float ti[8] = {ta.x, ta.y, ta.z, ta.w, tb.x, tb.y, tb.z, tb.w};
            #pragma unroll
            for (int k = 0; k < 8; ++k) {
                const int i = i0 + ch * 8 + k;
                const float dt  = ti[k] - tjv;
                const float dps = fmaf(pi[k], LOG2E, npjl);
                const float ny  = (dt < 0.0f) ? dps : -dps;
                const float e   = __builtin_amdgcn_exp2f(ny);
                const float lg  = __builtin_amdgcn_logf(1.0f + e);
                const bool valid = (i < j) && (fabsf(dt) > MIN_DIFF_C);
                s = fmaf(valid ? fabsf(dt) : 0.0f, lg, s);
                c += valid ? 1.0f : 0.0f;
            }
        }
        // exactly one diag chunk per j-tile carries the MSE term
        if (ic == 4 * t + 3) { const float d = pj - tjv; r = d * d; }
    }

    // ---- block reduction: wave shuffle (64) then LDS across 4 waves ----
    #pragma unroll
    for (int off = 32; off > 0; off >>= 1) {
        s += __shfl_down(s, off, 64);
        c += __shfl_down(c, off, 64);
        r += __shfl_down(r, off, 64);
    }
    __shared__ float red_s[4], red_c[4], red_r[4];
    const int wave = tid >> 6;
    const int lane = tid & 63;
    if (lane == 0) { red_s[wave] = s; red_c[wave] = c; red_r[wave] = r; }
    __syncthreads();
    if (tid == 0) {
        parts[b] = make_float4(red_s[0] + red_s[1] + red_s[2] + red_s[3],
                               red_c[0] + red_c[1] + red_c[2] + red_c[3],
                               red_r[0] + red_r[1] + red_r[2] + red_r[3], 0.0f);
    }
}

__global__ __launch_bounds__(256) void finalize_kernel(
    const float4* __restrict__ parts, float* __restrict__ out) {
    float s = 0.0f, c = 0.0f, r = 0.0f;
    for (int i = threadIdx.x; i < NBLOCKS; i += 256) {
        const float4 v = parts[i];
        s += v.x; c += v.y; r += v.z;
    }
    #pragma unroll
    for (int off = 32; off > 0; off >>= 1) {
        s += __shfl_down(s, off, 64);
        c += __shfl_down(c, off, 64);
        r += __shfl_down(r, off, 64);
    }
    __shared__ float red_s[4], red_c[4], red_r[4];
    const int wave = threadIdx.x >> 6;
    const int lane = threadIdx.x & 63;
    if (lane == 0) { red_s[wave] = s; red_c[wave] = c; red_r[wave] = r; }
    __syncthreads();
    if (threadIdx.x == 0) {
        const float fs = red_s[0] + red_s[1] + red_s[2] + red_s[3];
        const float fc = red_c[0] + red_c[1] + red_c[2] + red_c[3];
        const float fr = red_r[0] + red_r[1] + red_r[2] + red_r[3];
        const float reg = fr / (float)NN;
        const float pm  = LN2 * fs / fmaxf(fc, 1.0f);
        out[0] = (fc > 0.0f) ? (reg + ALPHA_C * pm) : reg;
    }
}

extern "C" void kernel_launch(void* const* d_in, const int* in_sizes, int n_in,
                              void* d_out, int out_size, void* d_ws, size_t ws_size,
                              hipStream_t stream) {
    const float* pred = (const float*)d_in[0];
    const float* targ = (const float*)d_in[1];
    float* out = (float*)d_out;
    float4* parts = (float4*)d_ws;   // NBLOCKS * 16 B = 33,792 B

    pair_kernel<<<NBLOCKS, 256, 0, stream>>>(pred, targ, parts);
    finalize_kernel<<<1, 256, 0, stream>>>(parts, out);
}

// Round 4
// 136.502 us; speedup vs baseline: 1.0860x; 1.0860x over previous
//
#include <hip/hip_runtime.h>
#include <math.h>

#define NN 8192
#define JT 256                         // j-tile width = block size
#define IC 64                          // i-chunk per block
#define NJT (NN / JT)                  // 32 j-tiles
#define NBLOCKS (2 * NJT * (NJT + 1))  // 2112 blocks
#define ALPHA_C 3.0f
#define MIN_DIFF_C 0.1f
#define LOG2E 1.44269504088896340736f
#define LN2   0.69314718055994530942f

// Block b covers j in [t*256, t*256+256) x i in [ic*64, ic*64+64).
// i-loads are block-uniform float4s consumed component-wise — NO local
// arrays (R2's pi[8]/ti[8] spilled to scratch: 23 MB WRITE_SIZE).
// -log_sigmoid(x) = ln2 * log2(1 + 2^(-x*log2e)); ln2 folded into finalize.

// One pair: PV/TV are pred_i/targ_i, VEXTRA is the extra validity predicate.
#define PAIR_BODY(PV, TV, VEXTRA)                                       \
    {                                                                   \
        const float dt  = (TV) - tjv;                                   \
        const float dps = fmaf((PV), LOG2E, npjl);  /* (pi-pj)*log2e */ \
        const float ny  = (dt < 0.0f) ? dps : -dps; /* -x*log2e */      \
        const float e   = __builtin_amdgcn_exp2f(ny);                   \
        const float lg  = __builtin_amdgcn_logf(1.0f + e);              \
        const bool valid = (VEXTRA) && (fabsf(dt) > MIN_DIFF_C);        \
        s = fmaf(valid ? fabsf(dt) : 0.0f, lg, s);                      \
        c += valid ? 1.0f : 0.0f;                                       \
    }

__global__ __launch_bounds__(256, 8) void pair_kernel(
    const float* __restrict__ pred, const float* __restrict__ targ,
    float4* __restrict__ parts) {
    const int b = blockIdx.x;
    // decode b -> (t, ic): blocks before j-tile t = 2*t*(t+1)
    int t = (int)((sqrt(1.0 + 2.0 * (double)b) - 1.0) * 0.5);
    while (2 * (t + 1) * (t + 2) <= b) ++t;
    while (2 * t * (t + 1) > b) --t;
    const int ic = b - 2 * t * (t + 1);
    const int j0 = t * JT;
    const int i0 = ic * IC;

    const int tid = threadIdx.x;
    const int j = j0 + tid;
    const float pj   = pred[j];
    const float tjv  = targ[j];
    const float npjl = -pj * LOG2E;

    float s = 0.0f;  // sum conf * log2(1+2^-y)   (ln2 applied later)
    float c = 0.0f;  // masked pair count
    float r = 0.0f;  // regression partial

    const bool diag = (ic >= 4 * t);

    if (!diag) {
        #pragma unroll
        for (int ch = 0; ch < IC / 8; ++ch) {
            const float4 pa = *(const float4*)(pred + i0 + ch * 8);
            const float4 pb = *(const float4*)(pred + i0 + ch * 8 + 4);
            const float4 ta = *(const float4*)(targ + i0 + ch * 8);
            const float4 tb = *(const float4*)(targ + i0 + ch * 8 + 4);
            PAIR_BODY(pa.x, ta.x, true)
            PAIR_BODY(pa.y, ta.y, true)
            PAIR_BODY(pa.z, ta.z, true)
            PAIR_BODY(pa.w, ta.w, true)
            PAIR_BODY(pb.x, tb.x, true)
            PAIR_BODY(pb.y, tb.y, true)
            PAIR_BODY(pb.z, tb.z, true)
            PAIR_BODY(pb.w, tb.w, true)
        }
    } else {
        #pragma unroll
        for (int ch = 0; ch < IC / 8; ++ch) {
            const int ib = i0 + ch * 8;
            const float4 pa = *(const float4*)(pred + ib);
            const float4 pb = *(const float4*)(pred + ib + 4);
            const float4 ta = *(const float4*)(targ + ib);
            const float4 tb = *(const float4*)(targ + ib + 4);
            PAIR_BODY(pa.x, ta.x, (ib + 0) < j)
            PAIR_BODY(pa.y, ta.y, (ib + 1) < j)
            PAIR_BODY(pa.z, ta.z, (ib + 2) < j)
            PAIR_BODY(pa.w, ta.w, (ib + 3) < j)
            PAIR_BODY(pb.x, tb.x, (ib + 4) < j)
            PAIR_BODY(pb.y, tb.y, (ib + 5) < j)
            PAIR_BODY(pb.z, tb.z, (ib + 6) < j)
            PAIR_BODY(pb.w, tb.w, (ib + 7) < j)
        }
        // exactly one diagonal chunk per j-tile carries the MSE term
        if (ic == 4 * t + 3) { const float d = pj - tjv; r = d * d; }
    }

    // ---- block reduction: wave shuffle (64) then LDS across 4 waves ----
    #pragma unroll
    for (int off = 32; off > 0; off >>= 1) {
        s += __shfl_down(s, off, 64);
        c += __shfl_down(c, off, 64);
        r += __shfl_down(r, off, 64);
    }
    __shared__ float red_s[4], red_c[4], red_r[4];
    const int wave = tid >> 6;
    const int lane = tid & 63;
    if (lane == 0) { red_s[wave] = s; red_c[wave] = c; red_r[wave] = r; }
    __syncthreads();
    if (tid == 0) {
        parts[b] = make_float4(red_s[0] + red_s[1] + red_s[2] + red_s[3],
                               red_c[0] + red_c[1] + red_c[2] + red_c[3],
                               red_r[0] + red_r[1] + red_r[2] + red_r[3], 0.0f);
    }
}

__global__ __launch_bounds__(256) void finalize_kernel(
    const float4* __restrict__ parts, float* __restrict__ out) {
    float s = 0.0f, c = 0.0f, r = 0.0f;
    for (int i = threadIdx.x; i < NBLOCKS; i += 256) {
        const float4 v = parts[i];
        s += v.x; c += v.y; r += v.z;
    }
    #pragma unroll
    for (int off = 32; off > 0; off >>= 1) {
        s += __shfl_down(s, off, 64);
        c += __shfl_down(c, off, 64);
        r += __shfl_down(r, off, 64);
    }
    __shared__ float red_s[4], red_c[4], red_r[4];
    const int wave = threadIdx.x >> 6;
    const int lane = threadIdx.x & 63;
    if (lane == 0) { red_s[wave] = s; red_c[wave] = c; red_r[wave] = r; }
    __syncthreads();
    if (threadIdx.x == 0) {
        const float fs = red_s[0] + red_s[1] + red_s[2] + red_s[3];
        const float fc = red_c[0] + red_c[1] + red_c[2] + red_c[3];
        const float fr = red_r[0] + red_r[1] + red_r[2] + red_r[3];
        const float reg = fr / (float)NN;
        const float pm  = LN2 * fs / fmaxf(fc, 1.0f);
        out[0] = (fc > 0.0f) ? (reg + ALPHA_C * pm) : reg;
    }
}

extern "C" void kernel_launch(void* const* d_in, const int* in_sizes, int n_in,
                              void* d_out, int out_size, void* d_ws, size_t ws_size,
                              hipStream_t stream) {
    const float* pred = (const float*)d_in[0];
    const float* targ = (const float*)d_in[1];
    float* out = (float*)d_out;
    float4* parts = (float4*)d_ws;   // NBLOCKS * 16 B = 33,792 B

    pair_kernel<<<NBLOCKS, 256, 0, stream>>>(pred, targ, parts);
    finalize_kernel<<<1, 256, 0, stream>>>(parts, out);
}

// Round 5
// 74.894 us; speedup vs baseline: 1.9794x; 1.8226x over previous
//
#include <hip/hip_runtime.h>
#include <math.h>

#define NN 8192
#define JT 256                         // j-tile width = block size
#define IC 64                          // i-chunk per block
#define NJT (NN / JT)                  // 32 j-tiles
#define NBLOCKS (2 * NJT * (NJT + 1))  // 2112 blocks
#define ALPHA_C 3.0f
#define MIN_DIFF_C 0.1f
#define LOG2E 1.44269504088896340736f
#define LN2   0.69314718055994530942f

// Block b covers j in [t*256, t*256+256) x i in [ic*64, ic*64+64).
// i-chunk staged to LDS once (512 B); hot loop reads float2 broadcast from
// LDS (conflict-free). R2/R3's block-uniform VMEM loads spilled hoisted
// results to scratch (19-23 MB WRITE_SIZE); R1's LDS pattern had VGPR=16,
// WRITE=34 KB — this is that pattern on the fine 2112-block grid.
// -log_sigmoid(x) = ln2 * log2(1 + 2^(-x*log2e)); ln2 folded into finalize.

#define PAIR_BODY(PV, TV, VEXTRA)                                       \
    {                                                                   \
        const float dt  = (TV) - tjv;                                   \
        const float dps = fmaf((PV), LOG2E, npjl);  /* (pi-pj)*log2e */ \
        const float ny  = (dt < 0.0f) ? dps : -dps; /* -x*log2e */      \
        const float e   = __builtin_amdgcn_exp2f(ny);                   \
        const float lg  = __builtin_amdgcn_logf(1.0f + e);              \
        const bool valid = (VEXTRA) && (fabsf(dt) > MIN_DIFF_C);        \
        s = fmaf(valid ? fabsf(dt) : 0.0f, lg, s);                      \
        c += valid ? 1.0f : 0.0f;                                       \
    }

__global__ __launch_bounds__(256, 8) void pair_kernel(
    const float* __restrict__ pred, const float* __restrict__ targ,
    float4* __restrict__ parts) {
    const int b = blockIdx.x;
    // decode b -> (t, ic): blocks before j-tile t = 2*t*(t+1)
    int t = (int)((sqrt(1.0 + 2.0 * (double)b) - 1.0) * 0.5);
    while (2 * (t + 1) * (t + 2) <= b) ++t;
    while (2 * t * (t + 1) > b) --t;
    const int ic = b - 2 * t * (t + 1);
    const int j0 = t * JT;
    const int i0 = ic * IC;

    __shared__ float2 sIT[IC];       // (pred_i, targ_i) for the i-chunk
    const int tid = threadIdx.x;
    if (tid < IC) sIT[tid] = make_float2(pred[i0 + tid], targ[i0 + tid]);
    __syncthreads();

    const int j = j0 + tid;
    const float pj   = pred[j];
    const float tjv  = targ[j];
    const float npjl = -pj * LOG2E;

    float s = 0.0f;  // sum conf * log2(1+2^-y)   (ln2 applied later)
    float c = 0.0f;  // masked pair count
    float r = 0.0f;  // regression partial

    const bool diag = (ic >= 4 * t);

    if (!diag) {
        #pragma unroll 8
        for (int ii = 0; ii < IC; ++ii) {
            const float2 v = sIT[ii];
            PAIR_BODY(v.x, v.y, true)
        }
    } else {
        #pragma unroll 8
        for (int ii = 0; ii < IC; ++ii) {
            const float2 v = sIT[ii];
            PAIR_BODY(v.x, v.y, (i0 + ii) < j)
        }
        // exactly one diagonal chunk per j-tile carries the MSE term
        if (ic == 4 * t + 3) { const float d = pj - tjv; r = d * d; }
    }

    // ---- block reduction: wave shuffle (64) then LDS across 4 waves ----
    #pragma unroll
    for (int off = 32; off > 0; off >>= 1) {
        s += __shfl_down(s, off, 64);
        c += __shfl_down(c, off, 64);
        r += __shfl_down(r, off, 64);
    }
    __shared__ float red_s[4], red_c[4], red_r[4];
    const int wave = tid >> 6;
    const int lane = tid & 63;
    if (lane == 0) { red_s[wave] = s; red_c[wave] = c; red_r[wave] = r; }
    __syncthreads();
    if (tid == 0) {
        parts[b] = make_float4(red_s[0] + red_s[1] + red_s[2] + red_s[3],
                               red_c[0] + red_c[1] + red_c[2] + red_c[3],
                               red_r[0] + red_r[1] + red_r[2] + red_r[3], 0.0f);
    }
}

__global__ __launch_bounds__(256) void finalize_kernel(
    const float4* __restrict__ parts, float* __restrict__ out) {
    float s = 0.0f, c = 0.0f, r = 0.0f;
    for (int i = threadIdx.x; i < NBLOCKS; i += 256) {
        const float4 v = parts[i];
        s += v.x; c += v.y; r += v.z;
    }
    #pragma unroll
    for (int off = 32; off > 0; off >>= 1) {
        s += __shfl_down(s, off, 64);
        c += __shfl_down(c, off, 64);
        r += __shfl_down(r, off, 64);
    }
    __shared__ float red_s[4], red_c[4], red_r[4];
    const int wave = threadIdx.x >> 6;
    const int lane = threadIdx.x & 63;
    if (lane == 0) { red_s[wave] = s; red_c[wave] = c; red_r[wave] = r; }
    __syncthreads();
    if (threadIdx.x == 0) {
        const float fs = red_s[0] + red_s[1] + red_s[2] + red_s[3];
        const float fc = red_c[0] + red_c[1] + red_c[2] + red_c[3];
        const float fr = red_r[0] + red_r[1] + red_r[2] + red_r[3];
        const float reg = fr / (float)NN;
        const float pm  = LN2 * fs / fmaxf(fc, 1.0f);
        out[0] = (fc > 0.0f) ? (reg + ALPHA_C * pm) : reg;
    }
}

extern "C" void kernel_launch(void* const* d_in, const int* in_sizes, int n_in,
                              void* d_out, int out_size, void* d_ws, size_t ws_size,
                              hipStream_t stream) {
    const float* pred = (const float*)d_in[0];
    const float* targ = (const float*)d_in[1];
    float* out = (float*)d_out;
    float4* parts = (float4*)d_ws;   // NBLOCKS * 16 B = 33,792 B

    pair_kernel<<<NBLOCKS, 256, 0, stream>>>(pred, targ, parts);
    finalize_kernel<<<1, 256, 0, stream>>>(parts, out);
}

// Round 6
// 71.149 us; speedup vs baseline: 2.0835x; 1.0526x over previous
//
#include <hip/hip_runtime.h>
#include <math.h>

#define NN 8192
#define JT 256                         // j-tile width = block size
#define IC 64                          // i-chunk per block
#define NJT (NN / JT)                  // 32 j-tiles
#define NBLOCKS (2 * NJT * (NJT + 1))  // 2112 blocks
#define ALPHA_C 3.0f
#define MIN_DIFF_C 0.1f
#define LOG2E 1.44269504088896340736f
#define LN2   0.69314718055994530942f

// Block b covers j in [t*256, t*256+256) x i in [ic*64, ic*64+64).
// i-chunk staged to LDS (512 B, broadcast reads, conflict-free) — the one
// structure proven spill-free (R4: WRITE ~34 KB vs R2/R3's 19-23 MB scratch).
// Slim inner loop: 8 VALU + 2 trans per pair; pair COUNT goes through
// __ballot + __popcll so it rides the scalar pipe (wave-uniform, no per-lane
// accumulator, no shuffle reduction for it).
// -log_sigmoid(x) = ln2 * log2(1 + 2^(-x*log2e)); ln2 folded into finalize.

__global__ __launch_bounds__(256, 8) void pair_kernel(
    const float* __restrict__ pred, const float* __restrict__ targ,
    float4* __restrict__ parts) {
    const int b = blockIdx.x;
    // decode b -> (t, ic): blocks before j-tile t = 2*t*(t+1)
    int t = (int)((sqrt(1.0 + 2.0 * (double)b) - 1.0) * 0.5);
    while (2 * (t + 1) * (t + 2) <= b) ++t;
    while (2 * t * (t + 1) > b) --t;
    const int ic = b - 2 * t * (t + 1);
    const int j0 = t * JT;
    const int i0 = ic * IC;

    __shared__ float2 sIT[IC];       // (pred_i, targ_i) for the i-chunk
    const int tid = threadIdx.x;
    if (tid < IC) sIT[tid] = make_float2(pred[i0 + tid], targ[i0 + tid]);
    __syncthreads();

    const int j = j0 + tid;
    const float pj   = pred[j];
    const float tjv  = targ[j];
    const float npjl = -pj * LOG2E;

    float s = 0.0f;            // sum conf * log2(1+2^-y)  (ln2 applied later)
    float r = 0.0f;            // regression partial
    unsigned int cnt = 0;      // wave-total masked-pair count (wave-uniform)

    const bool diag = (ic >= 4 * t);

    if (!diag) {
        #pragma unroll 8
        for (int ii = 0; ii < IC; ++ii) {
            const float2 v  = sIT[ii];
            const float dt  = v.y - tjv;                   // v_sub
            const float dps = fmaf(v.x, LOG2E, npjl);      // v_fma
            const float ny  = (dt < 0.0f) ? dps : -dps;    // v_cmp + v_cndmask(-mod)
            const float e   = __builtin_amdgcn_exp2f(ny);  // trans
            const float lg  = __builtin_amdgcn_logf(1.0f + e); // v_add + trans
            const bool valid = fabsf(dt) > MIN_DIFF_C;     // v_cmp (abs mod)
            const float cm  = valid ? fabsf(dt) : 0.0f;    // v_cndmask (abs mod)
            s = fmaf(cm, lg, s);                           // v_fma
            cnt += (unsigned int)__popcll(__ballot(valid)); // SALU: s_bcnt1+s_add
        }
    } else {
        #pragma unroll 8
        for (int ii = 0; ii < IC; ++ii) {
            const float2 v  = sIT[ii];
            const float dt  = v.y - tjv;
            const float dps = fmaf(v.x, LOG2E, npjl);
            const float ny  = (dt < 0.0f) ? dps : -dps;
            const float e   = __builtin_amdgcn_exp2f(ny);
            const float lg  = __builtin_amdgcn_logf(1.0f + e);
            const bool valid = ((i0 + ii) < j) && (fabsf(dt) > MIN_DIFF_C);
            const float cm  = valid ? fabsf(dt) : 0.0f;
            s = fmaf(cm, lg, s);
            cnt += (unsigned int)__popcll(__ballot(valid));
        }
        // exactly one diagonal chunk per j-tile carries the MSE term
        if (ic == 4 * t + 3) { const float d = pj - tjv; r = d * d; }
    }

    // ---- block reduction: shuffle s,r (64 lanes); cnt is wave-uniform ----
    #pragma unroll
    for (int off = 32; off > 0; off >>= 1) {
        s += __shfl_down(s, off, 64);
        r += __shfl_down(r, off, 64);
    }
    __shared__ float red_s[4], red_c[4], red_r[4];
    const int wave = tid >> 6;
    const int lane = tid & 63;
    if (lane == 0) { red_s[wave] = s; red_c[wave] = (float)cnt; red_r[wave] = r; }
    __syncthreads();
    if (tid == 0) {
        parts[b] = make_float4(red_s[0] + red_s[1] + red_s[2] + red_s[3],
                               red_c[0] + red_c[1] + red_c[2] + red_c[3],
                               red_r[0] + red_r[1] + red_r[2] + red_r[3], 0.0f);
    }
}

__global__ __launch_bounds__(256) void finalize_kernel(
    const float4* __restrict__ parts, float* __restrict__ out) {
    float s = 0.0f, c = 0.0f, r = 0.0f;
    for (int i = threadIdx.x; i < NBLOCKS; i += 256) {
        const float4 v = parts[i];
        s += v.x; c += v.y; r += v.z;
    }
    #pragma unroll
    for (int off = 32; off > 0; off >>= 1) {
        s += __shfl_down(s, off, 64);
        c += __shfl_down(c, off, 64);
        r += __shfl_down(r, off, 64);
    }
    __shared__ float red_s[4], red_c[4], red_r[4];
    const int wave = threadIdx.x >> 6;
    const int lane = threadIdx.x & 63;
    if (lane == 0) { red_s[wave] = s; red_c[wave] = c; red_r[wave] = r; }
    __syncthreads();
    if (threadIdx.x == 0) {
        const float fs = red_s[0] + red_s[1] + red_s[2] + red_s[3];
        const float fc = red_c[0] + red_c[1] + red_c[2] + red_c[3];
        const float fr = red_r[0] + red_r[1] + red_r[2] + red_r[3];
        const float reg = fr / (float)NN;
        const float pm  = LN2 * fs / fmaxf(fc, 1.0f);
        out[0] = (fc > 0.0f) ? (reg + ALPHA_C * pm) : reg;
    }
}

extern "C" void kernel_launch(void* const* d_in, const int* in_sizes, int n_in,
                              void* d_out, int out_size, void* d_ws, size_t ws_size,
                              hipStream_t stream) {
    const float* pred = (const float*)d_in[0];
    const float* targ = (const float*)d_in[1];
    float* out = (float*)d_out;
    float4* parts = (float4*)d_ws;   // NBLOCKS * 16 B = 33,792 B

    pair_kernel<<<NBLOCKS, 256, 0, stream>>>(pred, targ, parts);
    finalize_kernel<<<1, 256, 0, stream>>>(parts, out);
}

// Round 7
// 70.479 us; speedup vs baseline: 2.1033x; 1.0095x over previous
//
#include <hip/hip_runtime.h>
#include <math.h>

#define NN 8192
#define JT 256                         // j-tile width = block size
#define IC 64                         // i-chunk per block
#define NJT (NN / JT)                  // 32 j-tiles
#define NBLOCKS (2 * NJT * (NJT + 1))  // 2112 blocks
#define ALPHA_C 3.0f
#define MIN_DIFF_C 0.1f
#define LOG2E 1.44269504088896340736f
#define LN2   0.69314718055994530942f

// Block b covers j in [t*256, t*256+256) x i in [ic*64, ic*64+64).
// i-chunk staged to LDS split arrays; hot loop reads float4 (ds_read_b128,
// broadcast, conflict-free). Sign select via XOR bit-trick (v_and+v_xor,
// negation folded into exp2's input modifier). Count via __ballot+__popcll
// on the scalar pipe. -log_sigmoid(x) = ln2*log2(1+2^(-x*log2e)); ln2 in
// finalize. (R2/R3 lesson: block-uniform VMEM unrolls spill to scratch —
// keep LDS broadcast; cap ds_reads in flight via unroll 4.)

#define PAIR_BODY(PV, TV, VEXTRA)                                          \
    {                                                                      \
        const float dt  = (TV) - tjv;                  /* v_sub */         \
        const float dps = fmaf((PV), LOG2E, npjl);     /* v_fma */         \
        const float xs  = __uint_as_float(__float_as_uint(dps) ^           \
                          (__float_as_uint(dt) & 0x80000000u)); /* and+xor */\
        const float e   = __builtin_amdgcn_exp2f(-xs); /* trans, -mod free */\
        const float lg  = __builtin_amdgcn_logf(1.0f + e); /* add + trans */\
        const bool valid = (VEXTRA) && (fabsf(dt) > MIN_DIFF_C); /* v_cmp */ \
        s = fmaf(valid ? fabsf(dt) : 0.0f, lg, s);     /* cndmask + fma */ \
        cnt += (unsigned int)__popcll(__ballot(valid)); /* SALU */         \
    }

__global__ __launch_bounds__(256, 8) void pair_kernel(
    const float* __restrict__ pred, const float* __restrict__ targ,
    float4* __restrict__ parts) {
    const int b = blockIdx.x;
    // decode b -> (t, ic): blocks before j-tile t = 2*t*(t+1)
    int t = (int)((sqrt(1.0 + 2.0 * (double)b) - 1.0) * 0.5);
    while (2 * (t + 1) * (t + 2) <= b) ++t;
    while (2 * t * (t + 1) > b) --t;
    const int ic = b - 2 * t * (t + 1);
    const int j0 = t * JT;
    const int i0 = ic * IC;

    __shared__ __align__(16) float sP[IC];
    __shared__ __align__(16) float sT[IC];
    const int tid = threadIdx.x;
    if (tid < IC) { sP[tid] = pred[i0 + tid]; sT[tid] = targ[i0 + tid]; }
    __syncthreads();

    const int j = j0 + tid;
    const float pj   = pred[j];
    const float tjv  = targ[j];
    const float npjl = -pj * LOG2E;

    float s = 0.0f;        // sum conf * log2(1+2^-y)   (ln2 applied later)
    float r = 0.0f;        // regression partial
    unsigned int cnt = 0;  // wave-total masked-pair count (wave-uniform)

    const bool diag = (ic >= 4 * t);

    if (!diag) {
        #pragma unroll 4
        for (int ii = 0; ii < IC; ii += 4) {
            const float4 p4 = *(const float4*)&sP[ii];  // ds_read_b128
            const float4 t4 = *(const float4*)&sT[ii];  // ds_read_b128
            PAIR_BODY(p4.x, t4.x, true)
            PAIR_BODY(p4.y, t4.y, true)
            PAIR_BODY(p4.z, t4.z, true)
            PAIR_BODY(p4.w, t4.w, true)
        }
    } else {
        #pragma unroll 4
        for (int ii = 0; ii < IC; ii += 4) {
            const float4 p4 = *(const float4*)&sP[ii];
            const float4 t4 = *(const float4*)&sT[ii];
            const int ib = i0 + ii;
            PAIR_BODY(p4.x, t4.x, (ib + 0) < j)
            PAIR_BODY(p4.y, t4.y, (ib + 1) < j)
            PAIR_BODY(p4.z, t4.z, (ib + 2) < j)
            PAIR_BODY(p4.w, t4.w, (ib + 3) < j)
        }
        // exactly one diagonal chunk per j-tile carries the MSE term
        if (ic == 4 * t + 3) { const float d = pj - tjv; r = d * d; }
    }

    // ---- block reduction: shuffle s,r (64 lanes); cnt is wave-uniform ----
    #pragma unroll
    for (int off = 32; off > 0; off >>= 1) {
        s += __shfl_down(s, off, 64);
        r += __shfl_down(r, off, 64);
    }
    __shared__ float red_s[4], red_c[4], red_r[4];
    const int wave = tid >> 6;
    const int lane = tid & 63;
    if (lane == 0) { red_s[wave] = s; red_c[wave] = (float)cnt; red_r[wave] = r; }
    __syncthreads();
    if (tid == 0) {
        parts[b] = make_float4(red_s[0] + red_s[1] + red_s[2] + red_s[3],
                               red_c[0] + red_c[1] + red_c[2] + red_c[3],
                               red_r[0] + red_r[1] + red_r[2] + red_r[3], 0.0f);
    }
}

__global__ __launch_bounds__(256) void finalize_kernel(
    const float4* __restrict__ parts, float* __restrict__ out) {
    float s = 0.0f, c = 0.0f, r = 0.0f;
    for (int i = threadIdx.x; i < NBLOCKS; i += 256) {
        const float4 v = parts[i];
        s += v.x; c += v.y; r += v.z;
    }
    #pragma unroll
    for (int off = 32; off > 0; off >>= 1) {
        s += __shfl_down(s, off, 64);
        c += __shfl_down(c, off, 64);
        r += __shfl_down(r, off, 64);
    }
    __shared__ float red_s[4], red_c[4], red_r[4];
    const int wave = threadIdx.x >> 6;
    const int lane = threadIdx.x & 63;
    if (lane == 0) { red_s[wave] = s; red_c[wave] = c; red_r[wave] = r; }
    __syncthreads();
    if (threadIdx.x == 0) {
        const float fs = red_s[0] + red_s[1] + red_s[2] + red_s[3];
        const float fc = red_c[0] + red_c[1] + red_c[2] + red_c[3];
        const float fr = red_r[0] + red_r[1] + red_r[2] + red_r[3];
        const float reg = fr / (float)NN;
        const float pm  = LN2 * fs / fmaxf(fc, 1.0f);
        out[0] = (fc > 0.0f) ? (reg + ALPHA_C * pm) : reg;
    }
}

extern "C" void kernel_launch(void* const* d_in, const int* in_sizes, int n_in,
                              void* d_out, int out_size, void* d_ws, size_t ws_size,
                              hipStream_t stream) {
    const float* pred = (const float*)d_in[0];
    const float* targ = (const float*)d_in[1];
    float* out = (float*)d_out;
    float4* parts = (float4*)d_ws;   // NBLOCKS * 16 B = 33,792 B

    pair_kernel<<<NBLOCKS, 256, 0, stream>>>(pred, targ, parts);
    finalize_kernel<<<1, 256, 0, stream>>>(parts, out);
}